// Round 5
// baseline (579.314 us; speedup 1.0000x reference)
//
#include <hip/hip_runtime.h>
#include <stdint.h>

#define SEQ 2048
#define MROWS 8192
#define LOG2E 1.44269504f

typedef __attribute__((ext_vector_type(8))) _Float16 f16x8;
typedef __attribute__((ext_vector_type(2))) __fp16 fp16x2_t;   // cvt_pkrtz return type
typedef __attribute__((ext_vector_type(8))) unsigned short ushort8;
typedef __attribute__((ext_vector_type(4))) unsigned short ushort4_t;
typedef __attribute__((ext_vector_type(4))) float f32x4;

__device__ __forceinline__ unsigned short f32_to_f16u(float f) {
  union { _Float16 h; unsigned short u; } v; v.h = (_Float16)f; return v.u;
}

// ---------------- fused QKV projection GEMM ----------------
// z=0: Q -> f16 plane (pre-scaled by log2e); z=1: K -> f16 plane;
// z=2: V -> per-head transposed f16
__global__ __launch_bounds__(256) void qkv_k(
    const float* __restrict__ Aq, const float* __restrict__ Ak, const float* __restrict__ Av,
    const float* __restrict__ Wq, const float* __restrict__ Wk, const float* __restrict__ Wv,
    const float* __restrict__ bq, const float* __restrict__ bk, const float* __restrict__ bv,
    unsigned short* __restrict__ Qf, unsigned short* __restrict__ Kf, unsigned short* __restrict__ Vt)
{
  const int z = blockIdx.z;
  const float* __restrict__ A    = (z==0)? Aq : (z==1)? Ak : Av;
  const float* __restrict__ W    = (z==0)? Wq : (z==1)? Wk : Wv;
  const float* __restrict__ bias = (z==0)? bq : (z==1)? bk : bv;

  __shared__ unsigned short Ah[128*32];
  __shared__ unsigned short Bh[128*32];

  const int tid  = threadIdx.x;
  const int lane = tid & 63;
  const int w    = tid >> 6;
  const int wm   = w >> 1, wn = w & 1;
  const int row0 = blockIdx.x * 128;
  const int col0 = blockIdx.y * 128;

  f32x4 acc[4][4] = {};

  for (int k0 = 0; k0 < 1024; k0 += 32) {
    __syncthreads();
    #pragma unroll
    for (int i = 0; i < 2; ++i) {
      int c = tid + i*256;            // 0..511 chunks of 8 elements
      int r = c >> 2, slot = c & 3;   // 128 rows x 4 slots
      int lidx = r*32 + ((slot ^ ((r >> 1) & 3))*8);
      {
        const float* ap = A + (size_t)(row0 + r)*1024 + k0 + slot*8;
        float4 f0 = *(const float4*)ap;
        float4 f1 = *(const float4*)(ap + 4);
        float fs[8] = {f0.x,f0.y,f0.z,f0.w,f1.x,f1.y,f1.z,f1.w};
        ushort8 hv;
        #pragma unroll
        for (int j=0;j<8;++j) hv[j] = f32_to_f16u(fs[j]);
        *(ushort8*)&Ah[lidx] = hv;
      }
      {
        const float* bp = W + (size_t)(col0 + r)*1024 + k0 + slot*8;
        float4 f0 = *(const float4*)bp;
        float4 f1 = *(const float4*)(bp + 4);
        float fs[8] = {f0.x,f0.y,f0.z,f0.w,f1.x,f1.y,f1.z,f1.w};
        ushort8 hv;
        #pragma unroll
        for (int j=0;j<8;++j) hv[j] = f32_to_f16u(fs[j]);
        *(ushort8*)&Bh[lidx] = hv;
      }
    }
    __syncthreads();

    f16x8 a_[4], b_[4];
    const int slotR = lane >> 4;
    #pragma unroll
    for (int m=0;m<4;++m) {
      int r = wm*64 + m*16 + (lane & 15);
      a_[m] = *(const f16x8*)&Ah[r*32 + ((slotR ^ ((r>>1)&3))*8)];
    }
    #pragma unroll
    for (int nn=0;nn<4;++nn) {
      int r = wn*64 + nn*16 + (lane & 15);
      b_[nn] = *(const f16x8*)&Bh[r*32 + ((slotR ^ ((r>>1)&3))*8)];
    }
    #pragma unroll
    for (int m=0;m<4;++m)
      #pragma unroll
      for (int nn=0;nn<4;++nn)
        acc[m][nn] = __builtin_amdgcn_mfma_f32_16x16x32_f16(a_[m], b_[nn], acc[m][nn],0,0,0);
  }

  // epilogue (C frag: col=lane&15, row=(lane>>4)*4+r)
  #pragma unroll
  for (int m=0;m<4;++m) {
    #pragma unroll
    for (int nn=0;nn<4;++nn) {
      int gcol = col0 + wn*64 + nn*16 + (lane & 15);
      float bsv = bias[gcol];
      if (z == 2) {
        int rbase = row0 + wm*64 + m*16 + (lane>>4)*4;
        int nIdx = rbase >> 11, s0 = rbase & 2047;
        ushort4_t pk;
        #pragma unroll
        for (int r2=0;r2<4;++r2) pk[r2] = f32_to_f16u(acc[m][nn][r2] + bsv);
        *(ushort4_t*)&Vt[((size_t)(nIdx*1024 + gcol))*2048 + s0] = pk;
      } else {
        unsigned short* __restrict__ dst = (z==0)? Qf : Kf;
        const float qsc = (z==0)? LOG2E : 1.0f;   // fold log2(e) into Q
        #pragma unroll
        for (int r2=0;r2<4;++r2) {
          int grow = row0 + wm*64 + m*16 + (lane>>4)*4 + r2;
          dst[(size_t)grow*1024 + gcol] = f32_to_f16u((acc[m][nn][r2] + bsv) * qsc);
        }
      }
    }
  }
}

// ---------------- output projection: out = AO(f16) @ Wo^T + bo (f32) -------
__global__ __launch_bounds__(256) void oproj_k(
    const unsigned short* __restrict__ AO, const float* __restrict__ W,
    const float* __restrict__ bias, float* __restrict__ out)
{
  __shared__ unsigned short Ah[128*32];
  __shared__ unsigned short Bh[128*32];

  const int tid  = threadIdx.x;
  const int lane = tid & 63;
  const int w    = tid >> 6;
  const int wm   = w >> 1, wn = w & 1;
  const int row0 = blockIdx.x * 128;
  const int col0 = blockIdx.y * 128;

  f32x4 acc[4][4] = {};

  for (int k0 = 0; k0 < 1024; k0 += 32) {
    __syncthreads();
    #pragma unroll
    for (int i = 0; i < 2; ++i) {
      int c = tid + i*256;
      int r = c >> 2, slot = c & 3;
      int lidx = r*32 + ((slot ^ ((r >> 1) & 3))*8);
      *(ushort8*)&Ah[lidx] = *(const ushort8*)&AO[(size_t)(row0 + r)*1024 + k0 + slot*8];
      {
        const float* bp = W + (size_t)(col0 + r)*1024 + k0 + slot*8;
        float4 f0 = *(const float4*)bp;
        float4 f1 = *(const float4*)(bp + 4);
        float fs[8] = {f0.x,f0.y,f0.z,f0.w,f1.x,f1.y,f1.z,f1.w};
        ushort8 hv;
        #pragma unroll
        for (int j=0;j<8;++j) hv[j] = f32_to_f16u(fs[j]);
        *(ushort8*)&Bh[lidx] = hv;
      }
    }
    __syncthreads();

    f16x8 a_[4], b_[4];
    const int slotR = lane >> 4;
    #pragma unroll
    for (int m=0;m<4;++m) {
      int r = wm*64 + m*16 + (lane & 15);
      a_[m] = *(const f16x8*)&Ah[r*32 + ((slotR ^ ((r>>1)&3))*8)];
    }
    #pragma unroll
    for (int nn=0;nn<4;++nn) {
      int r = wn*64 + nn*16 + (lane & 15);
      b_[nn] = *(const f16x8*)&Bh[r*32 + ((slotR ^ ((r>>1)&3))*8)];
    }
    #pragma unroll
    for (int m=0;m<4;++m)
      #pragma unroll
      for (int nn=0;nn<4;++nn)
        acc[m][nn] = __builtin_amdgcn_mfma_f32_16x16x32_f16(a_[m], b_[nn], acc[m][nn],0,0,0);
  }

  #pragma unroll
  for (int m=0;m<4;++m)
    #pragma unroll
    for (int nn=0;nn<4;++nn) {
      int gcol = col0 + wn*64 + nn*16 + (lane & 15);
      float bsv = bias[gcol];
      #pragma unroll
      for (int r2=0;r2<4;++r2) {
        int grow = row0 + wm*64 + m*16 + (lane>>4)*4 + r2;
        out[(size_t)grow*1024 + gcol] = acc[m][nn][r2] + bsv;
      }
    }
}

// ---------------- Flash attention: barrier-free, K/V direct from global ----
// grid 2048 blocks; XCD-swizzled so each XCD's L2 holds 8 heads' K+V (4MB).
// 4 waves x 16 q-rows, fully independent (only wave-private P LDS).
// QK^T as mfma(K,Q) -> S^T (lane owns q=lane&15); PV as mfma(V^T,P) -> O^T.
__global__ __launch_bounds__(256) void attn_k(
  const unsigned short* __restrict__ Qf, const unsigned short* __restrict__ Kf,
  const unsigned short* __restrict__ Vt, unsigned short* __restrict__ AO)
{
  __shared__ unsigned short Ps[4][16*64];   // per-wave P (16 q x 64 k, swizzled)

  const int tid = threadIdx.x, lane = tid & 63, w = tid >> 6;
  const int q = lane & 15, g = lane >> 4;

  // T1 XCD swizzle (bijective: 2048 % 8 == 0): consecutive logical blocks
  // (same head) land on the same XCD -> per-XCD L2 working set = 4MB.
  const int bid = blockIdx.x + gridDim.x * blockIdx.y;   // physical flat id
  const int swz = (bid & 7) * 256 + (bid >> 3);          // logical id
  const int qt = swz & 31, nh = swz >> 5;
  const int n = nh >> 4, h = nh & 15;

  // Q fragment (pre-scaled by log2e)
  f16x8 qf[2];
  {
    int qrow = n*SEQ + qt*64 + w*16 + q;
    #pragma unroll
    for (int ks=0; ks<2; ++ks)
      qf[ks] = *(const f16x8*)&Qf[(size_t)qrow*1024 + h*64 + ks*32 + g*8];
  }

  f32x4 o[4] = {};          // O^T frag: o[df][r] = O[q][d=df*16+4g+r]
  float mrun = -1e30f, lrun = 0.f;

  const size_t kbase = (size_t)(n*SEQ)*1024 + h*64;   // K plane [s][1024]
  const size_t vbase = ((size_t)(n*1024 + h*64))*SEQ; // Vt [d][s]

  for (int kt = 0; kt < 32; ++kt) {
    // ---- K fragments straight from global (L1/L2-resident) ----
    f16x8 kb[4][2];
    #pragma unroll
    for (int nf=0; nf<4; ++nf)
      #pragma unroll
      for (int ks=0; ks<2; ++ks)
        kb[nf][ks] = *(const f16x8*)&Kf[kbase + (size_t)(kt*64 + nf*16 + q)*1024 + ks*32 + g*8];

    // S^T = K * Q^T : s[nf][r] = S[q][k = nf*16 + 4g + r]
    f32x4 s[4];
    #pragma unroll
    for (int nf=0; nf<4; ++nf) s[nf] = f32x4{0.f,0.f,0.f,0.f};
    __builtin_amdgcn_s_setprio(1);
    #pragma unroll
    for (int nf=0; nf<4; ++nf)
      #pragma unroll
      for (int ks=0; ks<2; ++ks)
        s[nf] = __builtin_amdgcn_mfma_f32_16x16x32_f16(kb[nf][ks], qf[ks], s[nf],0,0,0);
    __builtin_amdgcn_s_setprio(0);

    // ---- online softmax, local-max-first (exp2 overlaps the shuffles) ----
    float ml = fmaxf(fmaxf(fmaxf(s[0][0],s[0][1]),fmaxf(s[0][2],s[0][3])),
                     fmaxf(fmaxf(s[1][0],s[1][1]),fmaxf(s[1][2],s[1][3])));
    float mh = fmaxf(fmaxf(fmaxf(s[2][0],s[2][1]),fmaxf(s[2][2],s[2][3])),
                     fmaxf(fmaxf(s[3][0],s[3][1]),fmaxf(s[3][2],s[3][3])));
    ml = fmaxf(ml, mh);
    float m1 = fmaxf(ml, __shfl_xor(ml, 16, 64));
    float m2 = fmaxf(m1, __shfl_xor(m1, 32, 64));
    // exp2 with LOCAL max (doesn't wait on shuffles)
    float pvv[16]; float rsl = 0.f;
    #pragma unroll
    for (int nf=0; nf<4; ++nf)
      #pragma unroll
      for (int r=0;r<4;++r) {
        float p = __builtin_amdgcn_exp2f(s[nf][r] - ml);
        pvv[nf*4+r] = p; rsl += p;
      }
    float mn = fmaxf(mrun, m2);
    float sc = __builtin_amdgcn_exp2f(mrun - mn);   // O/lrun rescale
    float ls = __builtin_amdgcn_exp2f(ml - mn);     // lane-local P rescale
    // cross-lane sum dangles off the critical path (lrun used only at end)
    float rsc = rsl * ls;
    rsc += __shfl_xor(rsc, 16, 64);
    rsc += __shfl_xor(rsc, 32, 64);
    lrun = lrun*sc + rsc;
    mrun = mn;
    #pragma unroll
    for (int df=0; df<4; ++df)
      #pragma unroll
      for (int r=0;r<4;++r) o[df][r] *= sc;

    // pack P*ls (f16) -> wave-private LDS: row q, k0 = nf*16 + 4g (8B)
    #pragma unroll
    for (int nf=0; nf<4; ++nf) {
      union { fp16x2_t h2[2]; ushort4_t u4; } pk;
      pk.h2[0] = __builtin_amdgcn_cvt_pkrtz(pvv[nf*4+0]*ls, pvv[nf*4+1]*ls);
      pk.h2[1] = __builtin_amdgcn_cvt_pkrtz(pvv[nf*4+2]*ls, pvv[nf*4+3]*ls);
      int gi = 2*nf + (g>>1);                       // 16B granule index
      int idx = q*64 + ((gi ^ (q&7))*8) + (g&1)*4;  // ushort units
      *(ushort4_t*)&Ps[w][idx] = pk.u4;
    }

    // O^T += V^T * P : pa frag has n=q, kk = 32*s2 + 8g + j (16B read)
    #pragma unroll
    for (int s2=0; s2<2; ++s2) {
      f16x8 pa = *(const f16x8*)&Ps[w][q*64 + (((4*s2+g) ^ (q&7))*8)];
      __builtin_amdgcn_s_setprio(1);
      #pragma unroll
      for (int df=0; df<4; ++df) {
        size_t voff = vbase + (size_t)(df*16 + q)*SEQ + kt*64 + s2*32 + g*8;
        f16x8 vb = *(const f16x8*)&Vt[voff];
        o[df] = __builtin_amdgcn_mfma_f32_16x16x32_f16(vb, pa, o[df],0,0,0);
      }
      __builtin_amdgcn_s_setprio(0);
    }
  }

  // epilogue: AO[qrow][h*64 + df*16 + 4g + r] = O/lsum
  float inv = 1.0f / lrun;
  int qrow = n*SEQ + qt*64 + w*16 + q;
  #pragma unroll
  for (int df=0; df<4; ++df)
    #pragma unroll
    for (int r=0;r<4;++r)
      AO[(size_t)qrow*1024 + h*64 + df*16 + g*4 + r] = f32_to_f16u(o[df][r] * inv);
}

extern "C" void kernel_launch(void* const* d_in, const int* in_sizes, int n_in,
                              void* d_out, int out_size, void* d_ws, size_t ws_size,
                              hipStream_t stream)
{
  (void)in_sizes; (void)n_in; (void)out_size; (void)ws_size;
  const float* query = (const float*)d_in[0];
  const float* key   = (const float*)d_in[1];
  const float* value = (const float*)d_in[2];
  const float* Wq = (const float*)d_in[3];
  const float* bq = (const float*)d_in[4];
  const float* Wk = (const float*)d_in[5];
  const float* bk = (const float*)d_in[6];
  const float* Wv = (const float*)d_in[7];
  const float* bv = (const float*)d_in[8];
  const float* Wo = (const float*)d_in[9];
  const float* bo = (const float*)d_in[10];
  float* out = (float*)d_out;

  unsigned short* ws = (unsigned short*)d_ws;
  const size_t PLANE = (size_t)MROWS * 1024;
  unsigned short* Qf = ws;
  unsigned short* Kf = Qf + PLANE;
  unsigned short* Vt = Kf + PLANE;   // [ (n*16+h)*64+d ][ s ]
  unsigned short* AO = Vt + PLANE;

  dim3 bb(256);
  qkv_k <<<dim3(64,8,3), bb, 0, stream>>>(query,key,value, Wq,Wk,Wv, bq,bk,bv, Qf,Kf,Vt);
  attn_k<<<dim3(32,64), bb, 0, stream>>>(Qf, Kf, Vt, AO);
  oproj_k<<<dim3(64,8), bb, 0, stream>>>(AO, Wo, bo, out);
}

// Round 6
// 258.171 us; speedup vs baseline: 2.2439x; 2.2439x over previous
//
#include <hip/hip_runtime.h>
#include <stdint.h>

#define SEQ 2048
#define MROWS 8192
#define LOG2E 1.44269504f

typedef __attribute__((ext_vector_type(8))) _Float16 f16x8;
typedef __attribute__((ext_vector_type(2))) __fp16 fp16x2_t;   // cvt_pkrtz return type
typedef __attribute__((ext_vector_type(8))) unsigned short ushort8;
typedef __attribute__((ext_vector_type(4))) unsigned short ushort4_t;
typedef __attribute__((ext_vector_type(4))) float f32x4;

__device__ __forceinline__ unsigned short f32_to_f16u(float f) {
  union { _Float16 h; unsigned short u; } v; v.h = (_Float16)f; return v.u;
}

// ---------------- fused QKV projection GEMM ----------------
// z=0: Q -> f16 plane (pre-scaled by log2e); z=1: K -> f16 plane;
// z=2: V -> per-head transposed f16
__global__ __launch_bounds__(256) void qkv_k(
    const float* __restrict__ Aq, const float* __restrict__ Ak, const float* __restrict__ Av,
    const float* __restrict__ Wq, const float* __restrict__ Wk, const float* __restrict__ Wv,
    const float* __restrict__ bq, const float* __restrict__ bk, const float* __restrict__ bv,
    unsigned short* __restrict__ Qf, unsigned short* __restrict__ Kf, unsigned short* __restrict__ Vt)
{
  const int z = blockIdx.z;
  const float* __restrict__ A    = (z==0)? Aq : (z==1)? Ak : Av;
  const float* __restrict__ W    = (z==0)? Wq : (z==1)? Wk : Wv;
  const float* __restrict__ bias = (z==0)? bq : (z==1)? bk : bv;

  __shared__ unsigned short Ah[128*32];
  __shared__ unsigned short Bh[128*32];

  const int tid  = threadIdx.x;
  const int lane = tid & 63;
  const int w    = tid >> 6;
  const int wm   = w >> 1, wn = w & 1;
  const int row0 = blockIdx.x * 128;
  const int col0 = blockIdx.y * 128;

  f32x4 acc[4][4] = {};

  for (int k0 = 0; k0 < 1024; k0 += 32) {
    __syncthreads();
    #pragma unroll
    for (int i = 0; i < 2; ++i) {
      int c = tid + i*256;            // 0..511 chunks of 8 elements
      int r = c >> 2, slot = c & 3;   // 128 rows x 4 slots
      int lidx = r*32 + ((slot ^ ((r >> 1) & 3))*8);
      {
        const float* ap = A + (size_t)(row0 + r)*1024 + k0 + slot*8;
        float4 f0 = *(const float4*)ap;
        float4 f1 = *(const float4*)(ap + 4);
        float fs[8] = {f0.x,f0.y,f0.z,f0.w,f1.x,f1.y,f1.z,f1.w};
        ushort8 hv;
        #pragma unroll
        for (int j=0;j<8;++j) hv[j] = f32_to_f16u(fs[j]);
        *(ushort8*)&Ah[lidx] = hv;
      }
      {
        const float* bp = W + (size_t)(col0 + r)*1024 + k0 + slot*8;
        float4 f0 = *(const float4*)bp;
        float4 f1 = *(const float4*)(bp + 4);
        float fs[8] = {f0.x,f0.y,f0.z,f0.w,f1.x,f1.y,f1.z,f1.w};
        ushort8 hv;
        #pragma unroll
        for (int j=0;j<8;++j) hv[j] = f32_to_f16u(fs[j]);
        *(ushort8*)&Bh[lidx] = hv;
      }
    }
    __syncthreads();

    f16x8 a_[4], b_[4];
    const int slotR = lane >> 4;
    #pragma unroll
    for (int m=0;m<4;++m) {
      int r = wm*64 + m*16 + (lane & 15);
      a_[m] = *(const f16x8*)&Ah[r*32 + ((slotR ^ ((r>>1)&3))*8)];
    }
    #pragma unroll
    for (int nn=0;nn<4;++nn) {
      int r = wn*64 + nn*16 + (lane & 15);
      b_[nn] = *(const f16x8*)&Bh[r*32 + ((slotR ^ ((r>>1)&3))*8)];
    }
    #pragma unroll
    for (int m=0;m<4;++m)
      #pragma unroll
      for (int nn=0;nn<4;++nn)
        acc[m][nn] = __builtin_amdgcn_mfma_f32_16x16x32_f16(a_[m], b_[nn], acc[m][nn],0,0,0);
  }

  // epilogue (C frag: col=lane&15, row=(lane>>4)*4+r)
  #pragma unroll
  for (int m=0;m<4;++m) {
    #pragma unroll
    for (int nn=0;nn<4;++nn) {
      int gcol = col0 + wn*64 + nn*16 + (lane & 15);
      float bsv = bias[gcol];
      if (z == 2) {
        int rbase = row0 + wm*64 + m*16 + (lane>>4)*4;
        int nIdx = rbase >> 11, s0 = rbase & 2047;
        ushort4_t pk;
        #pragma unroll
        for (int r2=0;r2<4;++r2) pk[r2] = f32_to_f16u(acc[m][nn][r2] + bsv);
        *(ushort4_t*)&Vt[((size_t)(nIdx*1024 + gcol))*2048 + s0] = pk;
      } else {
        unsigned short* __restrict__ dst = (z==0)? Qf : Kf;
        const float qsc = (z==0)? LOG2E : 1.0f;   // fold log2(e) into Q
        #pragma unroll
        for (int r2=0;r2<4;++r2) {
          int grow = row0 + wm*64 + m*16 + (lane>>4)*4 + r2;
          dst[(size_t)grow*1024 + gcol] = f32_to_f16u((acc[m][nn][r2] + bsv) * qsc);
        }
      }
    }
  }
}

// ---------------- output projection: out = AO(f16) @ Wo^T + bo (f32) -------
__global__ __launch_bounds__(256) void oproj_k(
    const unsigned short* __restrict__ AO, const float* __restrict__ W,
    const float* __restrict__ bias, float* __restrict__ out)
{
  __shared__ unsigned short Ah[128*32];
  __shared__ unsigned short Bh[128*32];

  const int tid  = threadIdx.x;
  const int lane = tid & 63;
  const int w    = tid >> 6;
  const int wm   = w >> 1, wn = w & 1;
  const int row0 = blockIdx.x * 128;
  const int col0 = blockIdx.y * 128;

  f32x4 acc[4][4] = {};

  for (int k0 = 0; k0 < 1024; k0 += 32) {
    __syncthreads();
    #pragma unroll
    for (int i = 0; i < 2; ++i) {
      int c = tid + i*256;
      int r = c >> 2, slot = c & 3;
      int lidx = r*32 + ((slot ^ ((r >> 1) & 3))*8);
      *(ushort8*)&Ah[lidx] = *(const ushort8*)&AO[(size_t)(row0 + r)*1024 + k0 + slot*8];
      {
        const float* bp = W + (size_t)(col0 + r)*1024 + k0 + slot*8;
        float4 f0 = *(const float4*)bp;
        float4 f1 = *(const float4*)(bp + 4);
        float fs[8] = {f0.x,f0.y,f0.z,f0.w,f1.x,f1.y,f1.z,f1.w};
        ushort8 hv;
        #pragma unroll
        for (int j=0;j<8;++j) hv[j] = f32_to_f16u(fs[j]);
        *(ushort8*)&Bh[lidx] = hv;
      }
    }
    __syncthreads();

    f16x8 a_[4], b_[4];
    const int slotR = lane >> 4;
    #pragma unroll
    for (int m=0;m<4;++m) {
      int r = wm*64 + m*16 + (lane & 15);
      a_[m] = *(const f16x8*)&Ah[r*32 + ((slotR ^ ((r>>1)&3))*8)];
    }
    #pragma unroll
    for (int nn=0;nn<4;++nn) {
      int r = wn*64 + nn*16 + (lane & 15);
      b_[nn] = *(const f16x8*)&Bh[r*32 + ((slotR ^ ((r>>1)&3))*8)];
    }
    #pragma unroll
    for (int m=0;m<4;++m)
      #pragma unroll
      for (int nn=0;nn<4;++nn)
        acc[m][nn] = __builtin_amdgcn_mfma_f32_16x16x32_f16(a_[m], b_[nn], acc[m][nn],0,0,0);
  }

  #pragma unroll
  for (int m=0;m<4;++m)
    #pragma unroll
    for (int nn=0;nn<4;++nn) {
      int gcol = col0 + wn*64 + nn*16 + (lane & 15);
      float bsv = bias[gcol];
      #pragma unroll
      for (int r2=0;r2<4;++r2) {
        int grow = row0 + wm*64 + m*16 + (lane>>4)*4 + r2;
        out[(size_t)grow*1024 + gcol] = acc[m][nn][r2] + bsv;
      }
    }
}

// ---------------- Flash attention: K AND V staged in LDS, 32 q-rows/wave ---
// grid 1024 blocks (16 q-tiles of 128 x 64 heads), XCD-swizzled.
// 4 waves x 32 q-rows (qm=0,1); KVBLK=64, K/V double-buffered, 1 barrier/iter.
// QK^T as mfma(K,Q) -> S^T (lane owns q=lane&15); PV as mfma(V^T,P) -> O^T.
// K/V fragments and staged tiles shared across both qm halves.
__global__ __launch_bounds__(256) void attn_k(
  const unsigned short* __restrict__ Qf, const unsigned short* __restrict__ Kf,
  const unsigned short* __restrict__ Vt, unsigned short* __restrict__ AO)
{
  __shared__ unsigned short Ks[2][64*64];   // K tile (swizzled)
  __shared__ unsigned short Vs[2][64*64];   // V^T tile (swizzled)
  __shared__ unsigned short Ps[4][32*64];   // per-wave P (32 q x 64 k, swizzled)

  const int tid = threadIdx.x, lane = tid & 63, w = tid >> 6;
  const int q = lane & 15, g = lane >> 4;

  // T1 XCD swizzle (bijective: 1024 % 8 == 0): 128 consecutive logical blocks
  // per XCD = 8 heads -> per-XCD L2 working set = 8 x (K+V 512KB) = 4MB.
  const int bid = blockIdx.x;
  const int swz = (bid & 7) * 128 + (bid >> 3);
  const int qt = swz & 15, nh = swz >> 4;
  const int n = nh >> 4, h = nh & 15;

  // Q fragments (pre-scaled by log2e), 2 q-subtiles of 16 rows
  f16x8 qf[2][2];
  #pragma unroll
  for (int qm=0; qm<2; ++qm) {
    int qrow = n*SEQ + qt*128 + w*32 + qm*16 + q;
    #pragma unroll
    for (int ks=0; ks<2; ++ks)
      qf[qm][ks] = *(const f16x8*)&Qf[(size_t)qrow*1024 + h*64 + ks*32 + g*8];
  }

  f32x4 o[2][4] = {};       // O^T frags: o[qm][df][r] = O[q][d=df*16+4g+r]
  float mrun[2] = {-1e30f,-1e30f}, lrun[2] = {0.f,0.f};

  const size_t kbase = (size_t)(n*SEQ)*1024 + h*64;   // K plane [s][1024]
  const size_t vbase = ((size_t)(n*1024 + h*64))*SEQ; // Vt [d][s]

  // prologue: stage K/V tile 0 (64 x 64, 8-slot XOR swizzle)
  #pragma unroll
  for (int i=0;i<2;++i){
    int c = tid + i*256; int r = c>>3, sl = c&7;
    int lidx = r*64 + ((sl^(r&7))*8);
    *(ushort8*)&Ks[0][lidx] = *(const ushort8*)&Kf[kbase + (size_t)r*1024 + sl*8];
    *(ushort8*)&Vs[0][lidx] = *(const ushort8*)&Vt[vbase + (size_t)r*SEQ + sl*8];
  }
  __syncthreads();

  int cur = 0;
  for (int kt = 0; kt < 32; ++kt) {
    // ---- S^T = K * Q^T : s[qm][nf][r] = S[q][k = nf*16 + 4g + r] ----
    f32x4 s[2][4];
    #pragma unroll
    for (int qm=0;qm<2;++qm)
      #pragma unroll
      for (int nf=0; nf<4; ++nf) s[qm][nf] = f32x4{0.f,0.f,0.f,0.f};
    __builtin_amdgcn_s_setprio(1);
    #pragma unroll
    for (int nf=0; nf<4; ++nf) {
      int rr = nf*16 + q;
      #pragma unroll
      for (int ks=0; ks<2; ++ks) {
        f16x8 kb = *(const f16x8*)&Ks[cur][rr*64 + (((ks*4+g)^(q&7))*8)];
        s[0][nf] = __builtin_amdgcn_mfma_f32_16x16x32_f16(kb, qf[0][ks], s[0][nf],0,0,0);
        s[1][nf] = __builtin_amdgcn_mfma_f32_16x16x32_f16(kb, qf[1][ks], s[1][nf],0,0,0);
      }
    }
    __builtin_amdgcn_s_setprio(0);

    // ---- prefetch next K/V tile to regs (hides under softmax+PV) ----
    ushort8 kreg[2], vreg[2];
    if (kt < 31) {
      #pragma unroll
      for (int i=0;i<2;++i){
        int c = tid + i*256; int r = c>>3, sl = c&7;
        kreg[i] = *(const ushort8*)&Kf[kbase + (size_t)((kt+1)*64 + r)*1024 + sl*8];
        vreg[i] = *(const ushort8*)&Vt[vbase + (size_t)r*SEQ + (kt+1)*64 + sl*8];
      }
    }

    // ---- online softmax per q-subtile (local-max-first) + P pack ----
    #pragma unroll
    for (int qm=0; qm<2; ++qm) {
      float ml = fmaxf(fmaxf(fmaxf(s[qm][0][0],s[qm][0][1]),fmaxf(s[qm][0][2],s[qm][0][3])),
                       fmaxf(fmaxf(s[qm][1][0],s[qm][1][1]),fmaxf(s[qm][1][2],s[qm][1][3])));
      float mh = fmaxf(fmaxf(fmaxf(s[qm][2][0],s[qm][2][1]),fmaxf(s[qm][2][2],s[qm][2][3])),
                       fmaxf(fmaxf(s[qm][3][0],s[qm][3][1]),fmaxf(s[qm][3][2],s[qm][3][3])));
      ml = fmaxf(ml, mh);
      float m1 = fmaxf(ml, __shfl_xor(ml, 16, 64));
      float m2 = fmaxf(m1, __shfl_xor(m1, 32, 64));
      // exp2 with LOCAL max (doesn't wait on the shuffles)
      float pvv[16]; float rsl = 0.f;
      #pragma unroll
      for (int nf=0; nf<4; ++nf)
        #pragma unroll
        for (int r=0;r<4;++r) {
          float p = __builtin_amdgcn_exp2f(s[qm][nf][r] - ml);
          pvv[nf*4+r] = p; rsl += p;
        }
      float mn = fmaxf(mrun[qm], m2);
      float sc = __builtin_amdgcn_exp2f(mrun[qm] - mn);   // O/lrun rescale
      float ls = __builtin_amdgcn_exp2f(ml - mn);         // lane-local P rescale
      float rsc = rsl * ls;
      rsc += __shfl_xor(rsc, 16, 64);
      rsc += __shfl_xor(rsc, 32, 64);
      lrun[qm] = lrun[qm]*sc + rsc;
      mrun[qm] = mn;
      #pragma unroll
      for (int df=0; df<4; ++df)
        #pragma unroll
        for (int r=0;r<4;++r) o[qm][df][r] *= sc;

      // pack P*ls (f16) -> wave-private LDS row qm*16+q
      #pragma unroll
      for (int nf=0; nf<4; ++nf) {
        union { fp16x2_t h2[2]; ushort4_t u4; } pk;
        pk.h2[0] = __builtin_amdgcn_cvt_pkrtz(pvv[nf*4+0]*ls, pvv[nf*4+1]*ls);
        pk.h2[1] = __builtin_amdgcn_cvt_pkrtz(pvv[nf*4+2]*ls, pvv[nf*4+3]*ls);
        int gi = 2*nf + (g>>1);                       // 16B granule index
        int idx = (qm*16+q)*64 + ((gi ^ (q&7))*8) + (g&1)*4;
        *(ushort4_t*)&Ps[w][idx] = pk.u4;
      }
    }

    // ---- O^T += V^T * P  (V from LDS, shared across qm) ----
    #pragma unroll
    for (int s2=0; s2<2; ++s2) {
      int sl = 4*s2 + g;
      f16x8 pa0 = *(const f16x8*)&Ps[w][(q    )*64 + ((sl^(q&7))*8)];
      f16x8 pa1 = *(const f16x8*)&Ps[w][(16+q)*64 + ((sl^(q&7))*8)];
      __builtin_amdgcn_s_setprio(1);
      #pragma unroll
      for (int df=0; df<4; ++df) {
        f16x8 vb = *(const f16x8*)&Vs[cur][(df*16+q)*64 + ((sl^(q&7))*8)];
        o[0][df] = __builtin_amdgcn_mfma_f32_16x16x32_f16(vb, pa0, o[0][df],0,0,0);
        o[1][df] = __builtin_amdgcn_mfma_f32_16x16x32_f16(vb, pa1, o[1][df],0,0,0);
      }
      __builtin_amdgcn_s_setprio(0);
    }

    // ---- write staged tile to the other buffer; 1 barrier per iteration ----
    if (kt < 31) {
      #pragma unroll
      for (int i=0;i<2;++i){
        int c = tid + i*256; int r = c>>3, sl = c&7;
        int lidx = r*64 + ((sl^(r&7))*8);
        *(ushort8*)&Ks[cur^1][lidx] = kreg[i];
        *(ushort8*)&Vs[cur^1][lidx] = vreg[i];
      }
    }
    __syncthreads();
    cur ^= 1;
  }

  // epilogue: AO[qrow][h*64 + df*16 + 4g + r] = O/lsum
  #pragma unroll
  for (int qm=0; qm<2; ++qm) {
    float inv = 1.0f / lrun[qm];
    int qrow = n*SEQ + qt*128 + w*32 + qm*16 + q;
    #pragma unroll
    for (int df=0; df<4; ++df)
      #pragma unroll
      for (int r=0;r<4;++r)
        AO[(size_t)qrow*1024 + h*64 + df*16 + g*4 + r] = f32_to_f16u(o[qm][df][r] * inv);
  }
}

extern "C" void kernel_launch(void* const* d_in, const int* in_sizes, int n_in,
                              void* d_out, int out_size, void* d_ws, size_t ws_size,
                              hipStream_t stream)
{
  (void)in_sizes; (void)n_in; (void)out_size; (void)ws_size;
  const float* query = (const float*)d_in[0];
  const float* key   = (const float*)d_in[1];
  const float* value = (const float*)d_in[2];
  const float* Wq = (const float*)d_in[3];
  const float* bq = (const float*)d_in[4];
  const float* Wk = (const float*)d_in[5];
  const float* bk = (const float*)d_in[6];
  const float* Wv = (const float*)d_in[7];
  const float* bv = (const float*)d_in[8];
  const float* Wo = (const float*)d_in[9];
  const float* bo = (const float*)d_in[10];
  float* out = (float*)d_out;

  unsigned short* ws = (unsigned short*)d_ws;
  const size_t PLANE = (size_t)MROWS * 1024;
  unsigned short* Qf = ws;
  unsigned short* Kf = Qf + PLANE;
  unsigned short* Vt = Kf + PLANE;   // [ (n*16+h)*64+d ][ s ]
  unsigned short* AO = Vt + PLANE;

  dim3 bb(256);
  qkv_k <<<dim3(64,8,3), bb, 0, stream>>>(query,key,value, Wq,Wk,Wv, bq,bk,bv, Qf,Kf,Vt);
  attn_k<<<dim3(1024), bb, 0, stream>>>(Qf, Kf, Vt, AO);
  oproj_k<<<dim3(64,8), bb, 0, stream>>>(AO, Wo, bo, out);
}

// Round 7
// 251.437 us; speedup vs baseline: 2.3040x; 1.0268x over previous
//
#include <hip/hip_runtime.h>
#include <stdint.h>

#define SEQ 2048
#define MROWS 8192
#define LOG2E 1.44269504f

typedef __attribute__((ext_vector_type(8))) _Float16 f16x8;
typedef __attribute__((ext_vector_type(2))) __fp16 fp16x2_t;   // cvt_pkrtz return type
typedef __attribute__((ext_vector_type(8))) unsigned short ushort8;
typedef __attribute__((ext_vector_type(4))) unsigned short ushort4_t;
typedef __attribute__((ext_vector_type(4))) float f32x4;

__device__ __forceinline__ unsigned short f32_to_f16u(float f) {
  union { _Float16 h; unsigned short u; } v; v.h = (_Float16)f; return v.u;
}

// ---------------- fused QKV projection GEMM ----------------
// z=0: Q -> f16 plane (pre-scaled by log2e); z=1: K -> f16 plane;
// z=2: V -> per-head transposed f16
__global__ __launch_bounds__(256) void qkv_k(
    const float* __restrict__ Aq, const float* __restrict__ Ak, const float* __restrict__ Av,
    const float* __restrict__ Wq, const float* __restrict__ Wk, const float* __restrict__ Wv,
    const float* __restrict__ bq, const float* __restrict__ bk, const float* __restrict__ bv,
    unsigned short* __restrict__ Qf, unsigned short* __restrict__ Kf, unsigned short* __restrict__ Vt)
{
  const int z = blockIdx.z;
  const float* __restrict__ A    = (z==0)? Aq : (z==1)? Ak : Av;
  const float* __restrict__ W    = (z==0)? Wq : (z==1)? Wk : Wv;
  const float* __restrict__ bias = (z==0)? bq : (z==1)? bk : bv;

  __shared__ unsigned short Ah[128*32];
  __shared__ unsigned short Bh[128*32];

  const int tid  = threadIdx.x;
  const int lane = tid & 63;
  const int w    = tid >> 6;
  const int wm   = w >> 1, wn = w & 1;
  const int row0 = blockIdx.x * 128;
  const int col0 = blockIdx.y * 128;

  f32x4 acc[4][4] = {};

  for (int k0 = 0; k0 < 1024; k0 += 32) {
    __syncthreads();
    #pragma unroll
    for (int i = 0; i < 2; ++i) {
      int c = tid + i*256;            // 0..511 chunks of 8 elements
      int r = c >> 2, slot = c & 3;   // 128 rows x 4 slots
      int lidx = r*32 + ((slot ^ ((r >> 1) & 3))*8);
      {
        const float* ap = A + (size_t)(row0 + r)*1024 + k0 + slot*8;
        float4 f0 = *(const float4*)ap;
        float4 f1 = *(const float4*)(ap + 4);
        float fs[8] = {f0.x,f0.y,f0.z,f0.w,f1.x,f1.y,f1.z,f1.w};
        ushort8 hv;
        #pragma unroll
        for (int j=0;j<8;++j) hv[j] = f32_to_f16u(fs[j]);
        *(ushort8*)&Ah[lidx] = hv;
      }
      {
        const float* bp = W + (size_t)(col0 + r)*1024 + k0 + slot*8;
        float4 f0 = *(const float4*)bp;
        float4 f1 = *(const float4*)(bp + 4);
        float fs[8] = {f0.x,f0.y,f0.z,f0.w,f1.x,f1.y,f1.z,f1.w};
        ushort8 hv;
        #pragma unroll
        for (int j=0;j<8;++j) hv[j] = f32_to_f16u(fs[j]);
        *(ushort8*)&Bh[lidx] = hv;
      }
    }
    __syncthreads();

    f16x8 a_[4], b_[4];
    const int slotR = lane >> 4;
    #pragma unroll
    for (int m=0;m<4;++m) {
      int r = wm*64 + m*16 + (lane & 15);
      a_[m] = *(const f16x8*)&Ah[r*32 + ((slotR ^ ((r>>1)&3))*8)];
    }
    #pragma unroll
    for (int nn=0;nn<4;++nn) {
      int r = wn*64 + nn*16 + (lane & 15);
      b_[nn] = *(const f16x8*)&Bh[r*32 + ((slotR ^ ((r>>1)&3))*8)];
    }
    #pragma unroll
    for (int m=0;m<4;++m)
      #pragma unroll
      for (int nn=0;nn<4;++nn)
        acc[m][nn] = __builtin_amdgcn_mfma_f32_16x16x32_f16(a_[m], b_[nn], acc[m][nn],0,0,0);
  }

  // epilogue (C frag: col=lane&15, row=(lane>>4)*4+r)
  #pragma unroll
  for (int m=0;m<4;++m) {
    #pragma unroll
    for (int nn=0;nn<4;++nn) {
      int gcol = col0 + wn*64 + nn*16 + (lane & 15);
      float bsv = bias[gcol];
      if (z == 2) {
        int rbase = row0 + wm*64 + m*16 + (lane>>4)*4;
        int nIdx = rbase >> 11, s0 = rbase & 2047;
        ushort4_t pk;
        #pragma unroll
        for (int r2=0;r2<4;++r2) pk[r2] = f32_to_f16u(acc[m][nn][r2] + bsv);
        *(ushort4_t*)&Vt[((size_t)(nIdx*1024 + gcol))*2048 + s0] = pk;
      } else {
        unsigned short* __restrict__ dst = (z==0)? Qf : Kf;
        const float qsc = (z==0)? LOG2E : 1.0f;   // fold log2(e) into Q
        #pragma unroll
        for (int r2=0;r2<4;++r2) {
          int grow = row0 + wm*64 + m*16 + (lane>>4)*4 + r2;
          dst[(size_t)grow*1024 + gcol] = f32_to_f16u((acc[m][nn][r2] + bsv) * qsc);
        }
      }
    }
  }
}

// ---------------- output projection: out = AO(f16) @ Wo^T + bo (f32) -------
__global__ __launch_bounds__(256) void oproj_k(
    const unsigned short* __restrict__ AO, const float* __restrict__ W,
    const float* __restrict__ bias, float* __restrict__ out)
{
  __shared__ unsigned short Ah[128*32];
  __shared__ unsigned short Bh[128*32];

  const int tid  = threadIdx.x;
  const int lane = tid & 63;
  const int w    = tid >> 6;
  const int wm   = w >> 1, wn = w & 1;
  const int row0 = blockIdx.x * 128;
  const int col0 = blockIdx.y * 128;

  f32x4 acc[4][4] = {};

  for (int k0 = 0; k0 < 1024; k0 += 32) {
    __syncthreads();
    #pragma unroll
    for (int i = 0; i < 2; ++i) {
      int c = tid + i*256;
      int r = c >> 2, slot = c & 3;
      int lidx = r*32 + ((slot ^ ((r >> 1) & 3))*8);
      *(ushort8*)&Ah[lidx] = *(const ushort8*)&AO[(size_t)(row0 + r)*1024 + k0 + slot*8];
      {
        const float* bp = W + (size_t)(col0 + r)*1024 + k0 + slot*8;
        float4 f0 = *(const float4*)bp;
        float4 f1 = *(const float4*)(bp + 4);
        float fs[8] = {f0.x,f0.y,f0.z,f0.w,f1.x,f1.y,f1.z,f1.w};
        ushort8 hv;
        #pragma unroll
        for (int j=0;j<8;++j) hv[j] = f32_to_f16u(fs[j]);
        *(ushort8*)&Bh[lidx] = hv;
      }
    }
    __syncthreads();

    f16x8 a_[4], b_[4];
    const int slotR = lane >> 4;
    #pragma unroll
    for (int m=0;m<4;++m) {
      int r = wm*64 + m*16 + (lane & 15);
      a_[m] = *(const f16x8*)&Ah[r*32 + ((slotR ^ ((r>>1)&3))*8)];
    }
    #pragma unroll
    for (int nn=0;nn<4;++nn) {
      int r = wn*64 + nn*16 + (lane & 15);
      b_[nn] = *(const f16x8*)&Bh[r*32 + ((slotR ^ ((r>>1)&3))*8)];
    }
    #pragma unroll
    for (int m=0;m<4;++m)
      #pragma unroll
      for (int nn=0;nn<4;++nn)
        acc[m][nn] = __builtin_amdgcn_mfma_f32_16x16x32_f16(a_[m], b_[nn], acc[m][nn],0,0,0);
  }

  #pragma unroll
  for (int m=0;m<4;++m)
    #pragma unroll
    for (int nn=0;nn<4;++nn) {
      int gcol = col0 + wn*64 + nn*16 + (lane & 15);
      float bsv = bias[gcol];
      #pragma unroll
      for (int r2=0;r2<4;++r2) {
        int grow = row0 + wm*64 + m*16 + (lane>>4)*4 + r2;
        out[(size_t)grow*1024 + gcol] = acc[m][nn][r2] + bsv;
      }
    }
}

// ---------------- Flash attention: 40KB LDS (4 blk/CU), defer-max ----------
// grid 1024 blocks (16 q-tiles of 128 x 64 heads), XCD-swizzled.
// 4 waves x 32 q-rows (qm=0,1); KVBLK=64, K/V double-buffered, 1 barrier/iter.
// QK^T as mfma(K,Q) -> S^T (lane owns q=lane&15); PV as mfma(V^T,P) -> O^T.
// P buffer is 16 rows, reused across qm (wave-private, in-order).
// Defer-max (T13): common path skips max-shuffles + o-rescale entirely.
__global__ __launch_bounds__(256) void attn_k(
  const unsigned short* __restrict__ Qf, const unsigned short* __restrict__ Kf,
  const unsigned short* __restrict__ Vt, unsigned short* __restrict__ AO)
{
  __shared__ unsigned short Ks[2][64*64];   // K tile (swizzled)      16 KB
  __shared__ unsigned short Vs[2][64*64];   // V^T tile (swizzled)    16 KB
  __shared__ unsigned short Ps[4][16*64];   // per-wave P, reused/qm   8 KB

  const int tid = threadIdx.x, lane = tid & 63, w = tid >> 6;
  const int q = lane & 15, g = lane >> 4;

  // T1 XCD swizzle (bijective: 1024 % 8 == 0)
  const int bid = blockIdx.x;
  const int swz = (bid & 7) * 128 + (bid >> 3);
  const int qt = swz & 15, nh = swz >> 4;
  const int n = nh >> 4, h = nh & 15;

  // Q fragments (pre-scaled by log2e), 2 q-subtiles of 16 rows
  f16x8 qf[2][2];
  #pragma unroll
  for (int qm=0; qm<2; ++qm) {
    int qrow = n*SEQ + qt*128 + w*32 + qm*16 + q;
    #pragma unroll
    for (int ks=0; ks<2; ++ks)
      qf[qm][ks] = *(const f16x8*)&Qf[(size_t)qrow*1024 + h*64 + ks*32 + g*8];
  }

  f32x4 o[2][4] = {};       // O^T frags: o[qm][df][r] = O[q][d=df*16+4g+r]
  float mrun[2] = {-1e30f,-1e30f}, lrun[2] = {0.f,0.f};

  const size_t kbase = (size_t)(n*SEQ)*1024 + h*64;   // K plane [s][1024]
  const size_t vbase = ((size_t)(n*1024 + h*64))*SEQ; // Vt [d][s]

  // prologue: stage K/V tile 0 (64 x 64, 8-slot XOR swizzle)
  #pragma unroll
  for (int i=0;i<2;++i){
    int c = tid + i*256; int r = c>>3, sl = c&7;
    int lidx = r*64 + ((sl^(r&7))*8);
    *(ushort8*)&Ks[0][lidx] = *(const ushort8*)&Kf[kbase + (size_t)r*1024 + sl*8];
    *(ushort8*)&Vs[0][lidx] = *(const ushort8*)&Vt[vbase + (size_t)r*SEQ + sl*8];
  }
  __syncthreads();

  int cur = 0;
  for (int kt = 0; kt < 32; ++kt) {
    // ---- S^T = K * Q^T : s[qm][nf][r] = S[q][k = nf*16 + 4g + r] ----
    f32x4 s[2][4];
    #pragma unroll
    for (int qm=0;qm<2;++qm)
      #pragma unroll
      for (int nf=0; nf<4; ++nf) s[qm][nf] = f32x4{0.f,0.f,0.f,0.f};
    __builtin_amdgcn_s_setprio(1);
    #pragma unroll
    for (int nf=0; nf<4; ++nf) {
      int rr = nf*16 + q;
      #pragma unroll
      for (int ks=0; ks<2; ++ks) {
        f16x8 kb = *(const f16x8*)&Ks[cur][rr*64 + (((ks*4+g)^(q&7))*8)];
        s[0][nf] = __builtin_amdgcn_mfma_f32_16x16x32_f16(kb, qf[0][ks], s[0][nf],0,0,0);
        s[1][nf] = __builtin_amdgcn_mfma_f32_16x16x32_f16(kb, qf[1][ks], s[1][nf],0,0,0);
      }
    }
    __builtin_amdgcn_s_setprio(0);

    // ---- prefetch next K/V tile to regs (hides under softmax+PV) ----
    ushort8 kreg[2], vreg[2];
    if (kt < 31) {
      #pragma unroll
      for (int i=0;i<2;++i){
        int c = tid + i*256; int r = c>>3, sl = c&7;
        kreg[i] = *(const ushort8*)&Kf[kbase + (size_t)((kt+1)*64 + r)*1024 + sl*8];
        vreg[i] = *(const ushort8*)&Vt[vbase + (size_t)r*SEQ + (kt+1)*64 + sl*8];
      }
    }

    // ---- per q-subtile: softmax (defer-max) + P pack + PV ----
    #pragma unroll
    for (int qm=0; qm<2; ++qm) {
      // lane-local max over this lane's 16 S values
      float ml = fmaxf(fmaxf(fmaxf(s[qm][0][0],s[qm][0][1]),fmaxf(s[qm][0][2],s[qm][0][3])),
                       fmaxf(fmaxf(s[qm][1][0],s[qm][1][1]),fmaxf(s[qm][1][2],s[qm][1][3])));
      float mh = fmaxf(fmaxf(fmaxf(s[qm][2][0],s[qm][2][1]),fmaxf(s[qm][2][2],s[qm][2][3])),
                       fmaxf(fmaxf(s[qm][3][0],s[qm][3][1]),fmaxf(s[qm][3][2],s[qm][3][3])));
      ml = fmaxf(ml, mh);
      // defer-max vote on LOCAL max: covers every row's global max
      if (!__all(ml <= mrun[qm] + 7.0f)) {
        // slow path: grow the running max, rescale O and lsum
        float m1 = fmaxf(ml, __shfl_xor(ml, 16, 64));
        float m2 = fmaxf(m1, __shfl_xor(m1, 32, 64));
        float mn = fmaxf(mrun[qm], m2);
        float sc = __builtin_amdgcn_exp2f(mrun[qm] - mn);
        lrun[qm] *= sc;
        mrun[qm] = mn;
        #pragma unroll
        for (int df=0; df<4; ++df)
          #pragma unroll
          for (int r=0;r<4;++r) o[qm][df][r] *= sc;
      }
      // common path: exp2 off the running max directly (no fixup muls)
      float m0 = mrun[qm];
      float pvv[16]; float rsl = 0.f;
      #pragma unroll
      for (int nf=0; nf<4; ++nf)
        #pragma unroll
        for (int r=0;r<4;++r) {
          float p = __builtin_amdgcn_exp2f(s[qm][nf][r] - m0);
          pvv[nf*4+r] = p; rsl += p;
        }
      float rsc = rsl;
      rsc += __shfl_xor(rsc, 16, 64);
      rsc += __shfl_xor(rsc, 32, 64);
      lrun[qm] += rsc;

      // pack P (f16) -> wave-private LDS (16 rows, reused across qm)
      #pragma unroll
      for (int nf=0; nf<4; ++nf) {
        union { fp16x2_t h2[2]; ushort4_t u4; } pk;
        pk.h2[0] = __builtin_amdgcn_cvt_pkrtz(pvv[nf*4+0], pvv[nf*4+1]);
        pk.h2[1] = __builtin_amdgcn_cvt_pkrtz(pvv[nf*4+2], pvv[nf*4+3]);
        int gi = 2*nf + (g>>1);                       // 16B granule index
        int idx = q*64 + ((gi ^ (q&7))*8) + (g&1)*4;
        *(ushort4_t*)&Ps[w][idx] = pk.u4;
      }

      // O^T += V^T * P
      #pragma unroll
      for (int s2=0; s2<2; ++s2) {
        int sl = 4*s2 + g;
        f16x8 pa = *(const f16x8*)&Ps[w][q*64 + ((sl^(q&7))*8)];
        __builtin_amdgcn_s_setprio(1);
        #pragma unroll
        for (int df=0; df<4; ++df) {
          f16x8 vb = *(const f16x8*)&Vs[cur][(df*16+q)*64 + ((sl^(q&7))*8)];
          o[qm][df] = __builtin_amdgcn_mfma_f32_16x16x32_f16(vb, pa, o[qm][df],0,0,0);
        }
        __builtin_amdgcn_s_setprio(0);
      }
    }

    // ---- write staged tile to the other buffer; 1 barrier per iteration ----
    if (kt < 31) {
      #pragma unroll
      for (int i=0;i<2;++i){
        int c = tid + i*256; int r = c>>3, sl = c&7;
        int lidx = r*64 + ((sl^(r&7))*8);
        *(ushort8*)&Ks[cur^1][lidx] = kreg[i];
        *(ushort8*)&Vs[cur^1][lidx] = vreg[i];
      }
    }
    __syncthreads();
    cur ^= 1;
  }

  // epilogue: AO[qrow][h*64 + df*16 + 4g + r] = O/lsum
  #pragma unroll
  for (int qm=0; qm<2; ++qm) {
    float inv = 1.0f / lrun[qm];
    int qrow = n*SEQ + qt*128 + w*32 + qm*16 + q;
    #pragma unroll
    for (int df=0; df<4; ++df)
      #pragma unroll
      for (int r=0;r<4;++r)
        AO[(size_t)qrow*1024 + h*64 + df*16 + g*4 + r] = f32_to_f16u(o[qm][df][r] * inv);
  }
}

extern "C" void kernel_launch(void* const* d_in, const int* in_sizes, int n_in,
                              void* d_out, int out_size, void* d_ws, size_t ws_size,
                              hipStream_t stream)
{
  (void)in_sizes; (void)n_in; (void)out_size; (void)ws_size;
  const float* query = (const float*)d_in[0];
  const float* key   = (const float*)d_in[1];
  const float* value = (const float*)d_in[2];
  const float* Wq = (const float*)d_in[3];
  const float* bq = (const float*)d_in[4];
  const float* Wk = (const float*)d_in[5];
  const float* bk = (const float*)d_in[6];
  const float* Wv = (const float*)d_in[7];
  const float* bv = (const float*)d_in[8];
  const float* Wo = (const float*)d_in[9];
  const float* bo = (const float*)d_in[10];
  float* out = (float*)d_out;

  unsigned short* ws = (unsigned short*)d_ws;
  const size_t PLANE = (size_t)MROWS * 1024;
  unsigned short* Qf = ws;
  unsigned short* Kf = Qf + PLANE;
  unsigned short* Vt = Kf + PLANE;   // [ (n*16+h)*64+d ][ s ]
  unsigned short* AO = Vt + PLANE;

  dim3 bb(256);
  qkv_k <<<dim3(64,8,3), bb, 0, stream>>>(query,key,value, Wq,Wk,Wv, bq,bk,bv, Qf,Kf,Vt);
  attn_k<<<dim3(1024), bb, 0, stream>>>(Qf, Kf, Vt, AO);
  oproj_k<<<dim3(64,8), bb, 0, stream>>>(AO, Wo, bo, out);
}

// Round 8
// 221.551 us; speedup vs baseline: 2.6148x; 1.1349x over previous
//
#include <hip/hip_runtime.h>
#include <stdint.h>

#define SEQ 2048
#define MROWS 8192
#define LOG2E 1.44269504f

typedef __attribute__((ext_vector_type(8))) _Float16 f16x8;
typedef __attribute__((ext_vector_type(2))) __fp16 fp16x2_t;   // cvt_pkrtz return type
typedef __attribute__((ext_vector_type(8))) unsigned short ushort8;
typedef __attribute__((ext_vector_type(4))) unsigned short ushort4_t;
typedef __attribute__((ext_vector_type(4))) float f32x4;

__device__ __forceinline__ unsigned short f32_to_f16u(float f) {
  union { _Float16 h; unsigned short u; } v; v.h = (_Float16)f; return v.u;
}

__device__ __forceinline__ ushort8 pack8_rtz(float4 f0, float4 f1) {
  union { fp16x2_t h2[4]; ushort8 u8; } pk;
  pk.h2[0] = __builtin_amdgcn_cvt_pkrtz(f0.x, f0.y);
  pk.h2[1] = __builtin_amdgcn_cvt_pkrtz(f0.z, f0.w);
  pk.h2[2] = __builtin_amdgcn_cvt_pkrtz(f1.x, f1.y);
  pk.h2[3] = __builtin_amdgcn_cvt_pkrtz(f1.z, f1.w);
  return pk.u8;
}

// async global(16B/lane) -> LDS (wave-uniform base + lane*16)
__device__ __forceinline__ void gload16(const void* g, void* l) {
  __builtin_amdgcn_global_load_lds(
      (const __attribute__((address_space(1))) unsigned int*)g,
      (__attribute__((address_space(3))) unsigned int*)l, 16, 0, 0);
}

// ---------------- W f32 -> f16 conversion (4 planes of 1024x1024) ----------
__global__ __launch_bounds__(256) void wconv_k(
    const float* __restrict__ Wq, const float* __restrict__ Wk,
    const float* __restrict__ Wv, const float* __restrict__ Wo,
    unsigned short* __restrict__ WF)
{
  const int plane = blockIdx.y;
  const float* __restrict__ s = (plane==0)? Wq : (plane==1)? Wk : (plane==2)? Wv : Wo;
  size_t off = ((size_t)blockIdx.x*256 + threadIdx.x) * 8;
  float4 f0 = *(const float4*)(s + off);
  float4 f1 = *(const float4*)(s + off + 4);
  *(ushort8*)&WF[(size_t)plane*1048576 + off] = pack8_rtz(f0, f1);
}

// ---------------- fused QKV projection GEMM ----------------
// z=0: Q -> f16 plane (scaled by log2e); z=1: K; z=2: V -> per-head transposed
// A (f32) staged manually with cvt_pkrtz; B (f16 plane) via global_load_lds.
__global__ __launch_bounds__(256) void qkv_k(
    const float* __restrict__ Aq, const float* __restrict__ Ak, const float* __restrict__ Av,
    const unsigned short* __restrict__ WF,
    const float* __restrict__ bq, const float* __restrict__ bk, const float* __restrict__ bv,
    unsigned short* __restrict__ Qf, unsigned short* __restrict__ Kf, unsigned short* __restrict__ Vt)
{
  const int z = blockIdx.z;
  const float* __restrict__ A    = (z==0)? Aq : (z==1)? Ak : Av;
  const unsigned short* __restrict__ W = WF + (size_t)z*1048576;
  const float* __restrict__ bias = (z==0)? bq : (z==1)? bk : bv;

  __shared__ unsigned short Ah[128*32];
  __shared__ unsigned short Bh[128*32];

  const int tid  = threadIdx.x;
  const int lane = tid & 63;
  const int w    = tid >> 6;
  const int wm   = w >> 1, wn = w & 1;
  const int row0 = blockIdx.x * 128;
  const int col0 = blockIdx.y * 128;

  f32x4 acc[4][4] = {};

  for (int k0 = 0; k0 < 1024; k0 += 32) {
    __syncthreads();
    // ---- B tile via global_load_lds (pre-swizzled source, linear dest) ----
    #pragma unroll
    for (int j=0;j<2;++j) {
      int r  = w*32 + j*16 + (lane>>2);
      int sl = (lane & 3) ^ ((r>>1)&3);
      gload16(W + (size_t)(col0 + r)*1024 + k0 + sl*8, &Bh[(w*32 + j*16)*32]);
    }
    // ---- A tile manual (f32 -> f16 cvt_pkrtz) ----
    #pragma unroll
    for (int i = 0; i < 2; ++i) {
      int c = tid + i*256;            // 0..511 chunks of 8 elements
      int r = c >> 2, slot = c & 3;   // 128 rows x 4 slots
      int lidx = r*32 + ((slot ^ ((r >> 1) & 3))*8);
      const float* ap = A + (size_t)(row0 + r)*1024 + k0 + slot*8;
      float4 f0 = *(const float4*)ap;
      float4 f1 = *(const float4*)(ap + 4);
      *(ushort8*)&Ah[lidx] = pack8_rtz(f0, f1);
    }
    __syncthreads();

    f16x8 a_[4], b_[4];
    const int slotR = lane >> 4;
    #pragma unroll
    for (int m=0;m<4;++m) {
      int r = wm*64 + m*16 + (lane & 15);
      a_[m] = *(const f16x8*)&Ah[r*32 + ((slotR ^ ((r>>1)&3))*8)];
    }
    #pragma unroll
    for (int nn=0;nn<4;++nn) {
      int r = wn*64 + nn*16 + (lane & 15);
      b_[nn] = *(const f16x8*)&Bh[r*32 + ((slotR ^ ((r>>1)&3))*8)];
    }
    #pragma unroll
    for (int m=0;m<4;++m)
      #pragma unroll
      for (int nn=0;nn<4;++nn)
        acc[m][nn] = __builtin_amdgcn_mfma_f32_16x16x32_f16(a_[m], b_[nn], acc[m][nn],0,0,0);
  }

  // epilogue (C frag: col=lane&15, row=(lane>>4)*4+r)
  #pragma unroll
  for (int m=0;m<4;++m) {
    #pragma unroll
    for (int nn=0;nn<4;++nn) {
      int gcol = col0 + wn*64 + nn*16 + (lane & 15);
      float bsv = bias[gcol];
      if (z == 2) {
        int rbase = row0 + wm*64 + m*16 + (lane>>4)*4;
        int nIdx = rbase >> 11, s0 = rbase & 2047;
        ushort4_t pk;
        #pragma unroll
        for (int r2=0;r2<4;++r2) pk[r2] = f32_to_f16u(acc[m][nn][r2] + bsv);
        *(ushort4_t*)&Vt[((size_t)(nIdx*1024 + gcol))*2048 + s0] = pk;
      } else {
        unsigned short* __restrict__ dst = (z==0)? Qf : Kf;
        const float qsc = (z==0)? LOG2E : 1.0f;   // fold log2(e) into Q
        #pragma unroll
        for (int r2=0;r2<4;++r2) {
          int grow = row0 + wm*64 + m*16 + (lane>>4)*4 + r2;
          dst[(size_t)grow*1024 + gcol] = f32_to_f16u((acc[m][nn][r2] + bsv) * qsc);
        }
      }
    }
  }
}

// ---------------- output projection: out = AO(f16) @ WoF^T + bo (f32) ------
// BOTH operands staged via global_load_lds.
__global__ __launch_bounds__(256) void oproj_k(
    const unsigned short* __restrict__ AO, const unsigned short* __restrict__ W,
    const float* __restrict__ bias, float* __restrict__ out)
{
  __shared__ unsigned short Ah[128*32];
  __shared__ unsigned short Bh[128*32];

  const int tid  = threadIdx.x;
  const int lane = tid & 63;
  const int w    = tid >> 6;
  const int wm   = w >> 1, wn = w & 1;
  const int row0 = blockIdx.x * 128;
  const int col0 = blockIdx.y * 128;

  f32x4 acc[4][4] = {};

  for (int k0 = 0; k0 < 1024; k0 += 32) {
    __syncthreads();
    #pragma unroll
    for (int j=0;j<2;++j) {
      int r  = w*32 + j*16 + (lane>>2);
      int sl = (lane & 3) ^ ((r>>1)&3);
      gload16(AO + (size_t)(row0 + r)*1024 + k0 + sl*8, &Ah[(w*32 + j*16)*32]);
      gload16(W  + (size_t)(col0 + r)*1024 + k0 + sl*8, &Bh[(w*32 + j*16)*32]);
    }
    __syncthreads();

    f16x8 a_[4], b_[4];
    const int slotR = lane >> 4;
    #pragma unroll
    for (int m=0;m<4;++m) {
      int r = wm*64 + m*16 + (lane & 15);
      a_[m] = *(const f16x8*)&Ah[r*32 + ((slotR ^ ((r>>1)&3))*8)];
    }
    #pragma unroll
    for (int nn=0;nn<4;++nn) {
      int r = wn*64 + nn*16 + (lane & 15);
      b_[nn] = *(const f16x8*)&Bh[r*32 + ((slotR ^ ((r>>1)&3))*8)];
    }
    #pragma unroll
    for (int m=0;m<4;++m)
      #pragma unroll
      for (int nn=0;nn<4;++nn)
        acc[m][nn] = __builtin_amdgcn_mfma_f32_16x16x32_f16(a_[m], b_[nn], acc[m][nn],0,0,0);
  }

  #pragma unroll
  for (int m=0;m<4;++m)
    #pragma unroll
    for (int nn=0;nn<4;++nn) {
      int gcol = col0 + wn*64 + nn*16 + (lane & 15);
      float bsv = bias[gcol];
      #pragma unroll
      for (int r2=0;r2<4;++r2) {
        int grow = row0 + wm*64 + m*16 + (lane>>4)*4 + r2;
        out[(size_t)grow*1024 + gcol] = acc[m][nn][r2] + bsv;
      }
    }
}

// ---------------- Flash attention: shared V-reads + defer-max + lrun-defer -
// grid 1024 blocks (16 q-tiles of 128 x 64 heads), XCD-swizzled.
// 4 waves x 32 q-rows (qm=0,1); KVBLK=64, K/V double-buffered, 1 barrier/iter.
// QK^T as mfma(K,Q) -> S^T (lane owns q=lane&15); PV as mfma(V^T,P) -> O^T.
// P buffer 32 rows/wave so V fragments are read ONCE and feed both qm MFMAs.
// Defer-max (T13) skips max-shuffles + o-rescale; lrun shuffles deferred to
// the epilogue (lane-partial sums).
__global__ __launch_bounds__(256) void attn_k(
  const unsigned short* __restrict__ Qf, const unsigned short* __restrict__ Kf,
  const unsigned short* __restrict__ Vt, unsigned short* __restrict__ AO)
{
  __shared__ unsigned short Ks[2][64*64];   // K tile (swizzled)      16 KB
  __shared__ unsigned short Vs[2][64*64];   // V^T tile (swizzled)    16 KB
  __shared__ unsigned short Ps[4][32*64];   // per-wave P (32 q rows) 16 KB

  const int tid = threadIdx.x, lane = tid & 63, w = tid >> 6;
  const int q = lane & 15, g = lane >> 4;

  // T1 XCD swizzle (bijective: 1024 % 8 == 0)
  const int bid = blockIdx.x;
  const int swz = (bid & 7) * 128 + (bid >> 3);
  const int qt = swz & 15, nh = swz >> 4;
  const int n = nh >> 4, h = nh & 15;

  // Q fragments (pre-scaled by log2e), 2 q-subtiles of 16 rows
  f16x8 qf[2][2];
  #pragma unroll
  for (int qm=0; qm<2; ++qm) {
    int qrow = n*SEQ + qt*128 + w*32 + qm*16 + q;
    #pragma unroll
    for (int ks=0; ks<2; ++ks)
      qf[qm][ks] = *(const f16x8*)&Qf[(size_t)qrow*1024 + h*64 + ks*32 + g*8];
  }

  f32x4 o[2][4] = {};       // O^T frags: o[qm][df][r] = O[q][d=df*16+4g+r]
  float mrun[2] = {-1e30f,-1e30f}, lrun[2] = {0.f,0.f};  // lrun = LANE-partial

  const size_t kbase = (size_t)(n*SEQ)*1024 + h*64;   // K plane [s][1024]
  const size_t vbase = ((size_t)(n*1024 + h*64))*SEQ; // Vt [d][s]

  // prologue: stage K/V tile 0 (64 x 64, 8-slot XOR swizzle)
  #pragma unroll
  for (int i=0;i<2;++i){
    int c = tid + i*256; int r = c>>3, sl = c&7;
    int lidx = r*64 + ((sl^(r&7))*8);
    *(ushort8*)&Ks[0][lidx] = *(const ushort8*)&Kf[kbase + (size_t)r*1024 + sl*8];
    *(ushort8*)&Vs[0][lidx] = *(const ushort8*)&Vt[vbase + (size_t)r*SEQ + sl*8];
  }
  __syncthreads();

  int cur = 0;
  for (int kt = 0; kt < 32; ++kt) {
    // ---- S^T = K * Q^T : s[qm][nf][r] = S[q][k = nf*16 + 4g + r] ----
    f32x4 s[2][4];
    #pragma unroll
    for (int qm=0;qm<2;++qm)
      #pragma unroll
      for (int nf=0; nf<4; ++nf) s[qm][nf] = f32x4{0.f,0.f,0.f,0.f};
    __builtin_amdgcn_s_setprio(1);
    #pragma unroll
    for (int nf=0; nf<4; ++nf) {
      int rr = nf*16 + q;
      #pragma unroll
      for (int ks=0; ks<2; ++ks) {
        f16x8 kb = *(const f16x8*)&Ks[cur][rr*64 + (((ks*4+g)^(q&7))*8)];
        s[0][nf] = __builtin_amdgcn_mfma_f32_16x16x32_f16(kb, qf[0][ks], s[0][nf],0,0,0);
        s[1][nf] = __builtin_amdgcn_mfma_f32_16x16x32_f16(kb, qf[1][ks], s[1][nf],0,0,0);
      }
    }
    __builtin_amdgcn_s_setprio(0);

    // ---- prefetch next K/V tile to regs (hides under softmax+PV) ----
    ushort8 kreg[2], vreg[2];
    if (kt < 31) {
      #pragma unroll
      for (int i=0;i<2;++i){
        int c = tid + i*256; int r = c>>3, sl = c&7;
        kreg[i] = *(const ushort8*)&Kf[kbase + (size_t)((kt+1)*64 + r)*1024 + sl*8];
        vreg[i] = *(const ushort8*)&Vt[vbase + (size_t)r*SEQ + (kt+1)*64 + sl*8];
      }
    }

    // ---- softmax per q-subtile (defer-max), P pack to 32-row buffer ----
    #pragma unroll
    for (int qm=0; qm<2; ++qm) {
      float ml = fmaxf(fmaxf(fmaxf(s[qm][0][0],s[qm][0][1]),fmaxf(s[qm][0][2],s[qm][0][3])),
                       fmaxf(fmaxf(s[qm][1][0],s[qm][1][1]),fmaxf(s[qm][1][2],s[qm][1][3])));
      float mh = fmaxf(fmaxf(fmaxf(s[qm][2][0],s[qm][2][1]),fmaxf(s[qm][2][2],s[qm][2][3])),
                       fmaxf(fmaxf(s[qm][3][0],s[qm][3][1]),fmaxf(s[qm][3][2],s[qm][3][3])));
      ml = fmaxf(ml, mh);
      if (!__all(ml <= mrun[qm] + 7.0f)) {
        // slow path: grow running max, rescale O and lane-partial lsum
        float m1 = fmaxf(ml, __shfl_xor(ml, 16, 64));
        float m2 = fmaxf(m1, __shfl_xor(m1, 32, 64));
        float mn = fmaxf(mrun[qm], m2);
        float sc = __builtin_amdgcn_exp2f(mrun[qm] - mn);
        lrun[qm] *= sc;
        mrun[qm] = mn;
        #pragma unroll
        for (int df=0; df<4; ++df)
          #pragma unroll
          for (int r=0;r<4;++r) o[qm][df][r] *= sc;
      }
      float m0 = mrun[qm];
      float pvv[16]; float rsl = 0.f;
      #pragma unroll
      for (int nf=0; nf<4; ++nf)
        #pragma unroll
        for (int r=0;r<4;++r) {
          float p = __builtin_amdgcn_exp2f(s[qm][nf][r] - m0);
          pvv[nf*4+r] = p; rsl += p;
        }
      lrun[qm] += rsl;          // lane-partial; cross-lane reduce at epilogue

      #pragma unroll
      for (int nf=0; nf<4; ++nf) {
        union { fp16x2_t h2[2]; ushort4_t u4; } pk;
        pk.h2[0] = __builtin_amdgcn_cvt_pkrtz(pvv[nf*4+0], pvv[nf*4+1]);
        pk.h2[1] = __builtin_amdgcn_cvt_pkrtz(pvv[nf*4+2], pvv[nf*4+3]);
        int gi = 2*nf + (g>>1);                       // 16B granule index
        int idx = (qm*16+q)*64 + ((gi ^ (q&7))*8) + (g&1)*4;
        *(ushort4_t*)&Ps[w][idx] = pk.u4;
      }
    }

    // ---- O^T += V^T * P  (V fragment read once, feeds both qm) ----
    #pragma unroll
    for (int s2=0; s2<2; ++s2) {
      int sl = 4*s2 + g;
      f16x8 pa0 = *(const f16x8*)&Ps[w][(q    )*64 + ((sl^(q&7))*8)];
      f16x8 pa1 = *(const f16x8*)&Ps[w][(16+q)*64 + ((sl^(q&7))*8)];
      __builtin_amdgcn_s_setprio(1);
      #pragma unroll
      for (int df=0; df<4; ++df) {
        f16x8 vb = *(const f16x8*)&Vs[cur][(df*16+q)*64 + ((sl^(q&7))*8)];
        o[0][df] = __builtin_amdgcn_mfma_f32_16x16x32_f16(vb, pa0, o[0][df],0,0,0);
        o[1][df] = __builtin_amdgcn_mfma_f32_16x16x32_f16(vb, pa1, o[1][df],0,0,0);
      }
      __builtin_amdgcn_s_setprio(0);
    }

    // ---- write staged tile to the other buffer; 1 barrier per iteration ----
    if (kt < 31) {
      #pragma unroll
      for (int i=0;i<2;++i){
        int c = tid + i*256; int r = c>>3, sl = c&7;
        int lidx = r*64 + ((sl^(r&7))*8);
        *(ushort8*)&Ks[cur^1][lidx] = kreg[i];
        *(ushort8*)&Vs[cur^1][lidx] = vreg[i];
      }
    }
    __syncthreads();
    cur ^= 1;
  }

  // epilogue: cross-lane lsum reduce, then AO = O/lsum
  #pragma unroll
  for (int qm=0; qm<2; ++qm) {
    float rs = lrun[qm];
    rs += __shfl_xor(rs, 16, 64);
    rs += __shfl_xor(rs, 32, 64);
    float inv = 1.0f / rs;
    int qrow = n*SEQ + qt*128 + w*32 + qm*16 + q;
    #pragma unroll
    for (int df=0; df<4; ++df)
      #pragma unroll
      for (int r=0;r<4;++r)
        AO[(size_t)qrow*1024 + h*64 + df*16 + g*4 + r] = f32_to_f16u(o[qm][df][r] * inv);
  }
}

extern "C" void kernel_launch(void* const* d_in, const int* in_sizes, int n_in,
                              void* d_out, int out_size, void* d_ws, size_t ws_size,
                              hipStream_t stream)
{
  (void)in_sizes; (void)n_in; (void)out_size; (void)ws_size;
  const float* query = (const float*)d_in[0];
  const float* key   = (const float*)d_in[1];
  const float* value = (const float*)d_in[2];
  const float* Wq = (const float*)d_in[3];
  const float* bq = (const float*)d_in[4];
  const float* Wk = (const float*)d_in[5];
  const float* bk = (const float*)d_in[6];
  const float* Wv = (const float*)d_in[7];
  const float* bv = (const float*)d_in[8];
  const float* Wo = (const float*)d_in[9];
  const float* bo = (const float*)d_in[10];
  float* out = (float*)d_out;

  unsigned short* ws = (unsigned short*)d_ws;
  const size_t PLANE = (size_t)MROWS * 1024;
  unsigned short* Qf = ws;
  unsigned short* Kf = Qf + PLANE;
  unsigned short* Vt = Kf + PLANE;   // [ (n*16+h)*64+d ][ s ]
  unsigned short* AO = Vt + PLANE;
  unsigned short* WF = AO + PLANE;   // 4 x 1024x1024 f16 weight planes

  dim3 bb(256);
  wconv_k<<<dim3(512,4), bb, 0, stream>>>(Wq, Wk, Wv, Wo, WF);
  qkv_k <<<dim3(64,8,3), bb, 0, stream>>>(query,key,value, WF, bq,bk,bv, Qf,Kf,Vt);
  attn_k<<<dim3(1024), bb, 0, stream>>>(Qf, Kf, Vt, AO);
  oproj_k<<<dim3(64,8), bb, 0, stream>>>(AO, WF + 3*1048576, bo, out);
}